// Round 1
// baseline (830.012 us; speedup 1.0000x reference)
//
#include <hip/hip_runtime.h>

#define N_NODES 50000
#define NEDGE   800000
#define D       128
#define EPS     1e-5f

// ---------------- degree count ----------------
__global__ __launch_bounds__(256) void k_deg(const int* __restrict__ dst,
                                             int* __restrict__ degi) {
    int e = blockIdx.x * 256 + threadIdx.x;
    if (e < NEDGE) atomicAdd(&degi[dst[e]], 1);
}

// ---------------- exclusive scan (3 kernels) ----------------
__global__ __launch_bounds__(256) void k_scan1(const int* __restrict__ degi,
                                               int* __restrict__ offs,
                                               int* __restrict__ bsum) {
    __shared__ int s[256];
    int tid = threadIdx.x;
    int i = blockIdx.x * 256 + tid;
    int v = (i < N_NODES) ? degi[i] : 0;
    s[tid] = v;
    __syncthreads();
    for (int d = 1; d < 256; d <<= 1) {
        int t = (tid >= d) ? s[tid - d] : 0;
        __syncthreads();
        s[tid] += t;
        __syncthreads();
    }
    if (i < N_NODES) offs[i] = s[tid] - v;   // exclusive
    if (tid == 255) bsum[blockIdx.x] = s[255];
}

__global__ __launch_bounds__(256) void k_scan2(int* __restrict__ bsum, int nb) {
    __shared__ int s[256];
    int tid = threadIdx.x;
    int v = (tid < nb) ? bsum[tid] : 0;
    s[tid] = v;
    __syncthreads();
    for (int d = 1; d < 256; d <<= 1) {
        int t = (tid >= d) ? s[tid - d] : 0;
        __syncthreads();
        s[tid] += t;
        __syncthreads();
    }
    if (tid < nb) bsum[tid] = s[tid] - v;    // exclusive block offsets
}

__global__ __launch_bounds__(256) void k_scan3(const int* __restrict__ degi,
                                               const int* __restrict__ bsum,
                                               int* __restrict__ offs,
                                               int* __restrict__ cursor,
                                               float* __restrict__ invdeg) {
    int i = blockIdx.x * 256 + threadIdx.x;
    if (i < N_NODES) {
        int o = offs[i] + bsum[blockIdx.x];
        offs[i] = o;
        cursor[i] = o;
        int dg = degi[i];
        invdeg[i] = 1.0f / (float)(dg > 0 ? dg : 1);
    }
    if (i == 0 && blockIdx.x == 0) offs[N_NODES] = NEDGE;
}

// ---------------- CSR bucket fill ----------------
__global__ __launch_bounds__(256) void k_fill(const int* __restrict__ src,
                                              const int* __restrict__ dst,
                                              int* __restrict__ cursor,
                                              int* __restrict__ csr) {
    int e = blockIdx.x * 256 + threadIdx.x;
    if (e < NEDGE) {
        int p = atomicAdd(&cursor[dst[e]], 1);
        csr[p] = src[e];
    }
}

// ---------------- mean aggregation (gather over CSR) ----------------
// 8 nodes per 256-thread block; 32 lanes per node, float4 per lane (128 cols).
// Optionally applies BN(scale,shift)+ReLU to source features on read.
__global__ __launch_bounds__(256) void k_agg(const float* __restrict__ X,
                                             const int* __restrict__ offs,
                                             const int* __restrict__ csr,
                                             const float* __restrict__ invdeg,
                                             const float* __restrict__ bnscale,
                                             const float* __restrict__ bnshift,
                                             int useBn,
                                             float* __restrict__ HN) {
    int n = blockIdx.x * 8 + (threadIdx.x >> 5);
    if (n >= N_NODES) return;
    int c = (threadIdx.x & 31) * 4;

    float4 sc = {1.f, 1.f, 1.f, 1.f}, sh = {0.f, 0.f, 0.f, 0.f};
    if (useBn) {
        sc = *reinterpret_cast<const float4*>(bnscale + c);
        sh = *reinterpret_cast<const float4*>(bnshift + c);
    }
    int e0 = offs[n], e1 = offs[n + 1];
    float ax = 0.f, ay = 0.f, az = 0.f, aw = 0.f;
    for (int e = e0; e < e1; ++e) {
        int s = csr[e];
        float4 v = *reinterpret_cast<const float4*>(X + (size_t)s * D + c);
        if (useBn) {
            v.x = fmaxf(v.x * sc.x + sh.x, 0.f);
            v.y = fmaxf(v.y * sc.y + sh.y, 0.f);
            v.z = fmaxf(v.z * sc.z + sh.z, 0.f);
            v.w = fmaxf(v.w * sc.w + sh.w, 0.f);
        }
        ax += v.x; ay += v.y; az += v.z; aw += v.w;
    }
    float id = invdeg[n];
    float4 o = {ax * id, ay * id, az * id, aw * id};
    *reinterpret_cast<float4*>(HN + (size_t)n * D + c) = o;
}

// ---------------- fused GEMM: OUT = bnrelu?(X)@Ws + HN@Wn + b ----------------
// BM=64 rows, BN=128 cols (full), BK=32. 256 threads, 8x4 acc per thread.
// Optionally accumulates per-column sum/sumsq (BN stats) via LDS reduce + atomics.
__global__ __launch_bounds__(256) void k_gemm(const float* __restrict__ X,
                                              const float* __restrict__ HN,
                                              const float* __restrict__ Ws,
                                              const float* __restrict__ Wn,
                                              const float* __restrict__ bias,
                                              const float* __restrict__ bnscale,
                                              const float* __restrict__ bnshift,
                                              int useBn,
                                              float* __restrict__ OUT,
                                              int doStats,
                                              float* __restrict__ sums) {
    __shared__ float sX[64][32];
    __shared__ float sA[64][32];
    __shared__ float sWs[32][128];
    __shared__ float sWn[32][128];

    int tid = threadIdx.x;
    int row0 = blockIdx.x * 64;
    int tx = tid & 31;       // 32 col groups of 4
    int ty = tid >> 5;       // 8 row groups of 8

    float acc[8][4];
#pragma unroll
    for (int i = 0; i < 8; ++i)
#pragma unroll
        for (int j = 0; j < 4; ++j) acc[i][j] = 0.f;

    for (int k0 = 0; k0 < 128; k0 += 32) {
        // stage X and HN tiles: 64 rows x 32 k = 512 float4, 2 per thread
        for (int q = tid; q < 512; q += 256) {
            int r = q >> 3;
            int kk = (q & 7) * 4;
            int row = row0 + r;
            float4 xv = {0.f, 0.f, 0.f, 0.f};
            float4 av = {0.f, 0.f, 0.f, 0.f};
            if (row < N_NODES) {
                xv = *reinterpret_cast<const float4*>(X + (size_t)row * D + k0 + kk);
                av = *reinterpret_cast<const float4*>(HN + (size_t)row * D + k0 + kk);
                if (useBn) {
                    float4 s4 = *reinterpret_cast<const float4*>(bnscale + k0 + kk);
                    float4 h4 = *reinterpret_cast<const float4*>(bnshift + k0 + kk);
                    xv.x = fmaxf(xv.x * s4.x + h4.x, 0.f);
                    xv.y = fmaxf(xv.y * s4.y + h4.y, 0.f);
                    xv.z = fmaxf(xv.z * s4.z + h4.z, 0.f);
                    xv.w = fmaxf(xv.w * s4.w + h4.w, 0.f);
                }
            }
            *reinterpret_cast<float4*>(&sX[r][kk]) = xv;
            *reinterpret_cast<float4*>(&sA[r][kk]) = av;
        }
        // stage W chunks: 32 k x 128 cols = 1024 float4 each, 4 per thread
        for (int q = tid; q < 1024; q += 256) {
            int kk = q >> 5;
            int cc = (q & 31) * 4;
            *reinterpret_cast<float4*>(&sWs[kk][cc]) =
                *reinterpret_cast<const float4*>(Ws + (size_t)(k0 + kk) * D + cc);
            *reinterpret_cast<float4*>(&sWn[kk][cc]) =
                *reinterpret_cast<const float4*>(Wn + (size_t)(k0 + kk) * D + cc);
        }
        __syncthreads();

#pragma unroll
        for (int kk = 0; kk < 32; ++kk) {
            float4 w1 = *reinterpret_cast<float4*>(&sWs[kk][tx * 4]);
            float4 w2 = *reinterpret_cast<float4*>(&sWn[kk][tx * 4]);
#pragma unroll
            for (int i = 0; i < 8; ++i) {
                float xv = sX[ty * 8 + i][kk];
                float av = sA[ty * 8 + i][kk];
                acc[i][0] += xv * w1.x + av * w2.x;
                acc[i][1] += xv * w1.y + av * w2.y;
                acc[i][2] += xv * w1.z + av * w2.z;
                acc[i][3] += xv * w1.w + av * w2.w;
            }
        }
        __syncthreads();
    }

    // epilogue: bias, store, BN stats partials
    float4 b4 = *reinterpret_cast<const float4*>(bias + tx * 4);
    float cs[4] = {0.f, 0.f, 0.f, 0.f};
    float cq[4] = {0.f, 0.f, 0.f, 0.f};
#pragma unroll
    for (int i = 0; i < 8; ++i) {
        int row = row0 + ty * 8 + i;
        if (row < N_NODES) {
            float4 o;
            o.x = acc[i][0] + b4.x;
            o.y = acc[i][1] + b4.y;
            o.z = acc[i][2] + b4.z;
            o.w = acc[i][3] + b4.w;
            *reinterpret_cast<float4*>(OUT + (size_t)row * D + tx * 4) = o;
            if (doStats) {
                cs[0] += o.x; cq[0] += o.x * o.x;
                cs[1] += o.y; cq[1] += o.y * o.y;
                cs[2] += o.z; cq[2] += o.z * o.z;
                cs[3] += o.w; cq[3] += o.w * o.w;
            }
        }
    }
    if (doStats) {
        float* redS = &sX[0][0];   // 1024 floats needed, 2048 available
        float* redQ = &sA[0][0];
        __syncthreads();           // everyone past main loop
#pragma unroll
        for (int j = 0; j < 4; ++j) {
            redS[ty * 128 + tx * 4 + j] = cs[j];
            redQ[ty * 128 + tx * 4 + j] = cq[j];
        }
        __syncthreads();
        if (ty == 0) {
#pragma unroll
            for (int j = 0; j < 4; ++j) {
                float ts = 0.f, tq = 0.f;
#pragma unroll
                for (int g = 0; g < 8; ++g) {
                    ts += redS[g * 128 + tx * 4 + j];
                    tq += redQ[g * 128 + tx * 4 + j];
                }
                atomicAdd(&sums[tx * 4 + j], ts);
                atomicAdd(&sums[128 + tx * 4 + j], tq);
            }
        }
    }
}

// ---------------- BN finalize: per-column scale/shift ----------------
__global__ void k_bnfin(const float* __restrict__ sums,
                        const float* __restrict__ gamma,
                        const float* __restrict__ beta,
                        float* __restrict__ scale,
                        float* __restrict__ shift) {
    int c = threadIdx.x;  // 128 threads
    const float invN = 1.0f / (float)N_NODES;
    float mu = sums[c] * invN;
    float var = sums[128 + c] * invN - mu * mu;
    float s = gamma[c] * rsqrtf(var + EPS);
    scale[c] = s;
    shift[c] = beta[c] - mu * s;
}

// ---------------- launch ----------------
extern "C" void kernel_launch(void* const* d_in, const int* in_sizes, int n_in,
                              void* d_out, int out_size, void* d_ws, size_t ws_size,
                              hipStream_t stream) {
    const float* x   = (const float*)d_in[0];
    const int*   src = (const int*)d_in[1];
    const int*   dst = (const int*)d_in[2];
    const float* Ws1 = (const float*)d_in[3];
    const float* Wn1 = (const float*)d_in[4];
    const float* b1  = (const float*)d_in[5];
    const float* g1  = (const float*)d_in[6];
    const float* be1 = (const float*)d_in[7];
    const float* Ws2 = (const float*)d_in[8];
    const float* Wn2 = (const float*)d_in[9];
    const float* b2  = (const float*)d_in[10];
    const float* g2  = (const float*)d_in[11];
    const float* be2 = (const float*)d_in[12];
    const float* Ws3 = (const float*)d_in[13];
    const float* Wn3 = (const float*)d_in[14];
    const float* b3  = (const float*)d_in[15];
    float* out = (float*)d_out;

    char* p = (char*)d_ws;
    auto alloc = [&](size_t bytes) -> char* {
        char* r = p;
        p += (bytes + 255) & ~(size_t)255;
        return r;
    };
    float* hn     = (float*)alloc((size_t)N_NODES * D * 4);
    float* h1     = (float*)alloc((size_t)N_NODES * D * 4);
    float* h2     = (float*)alloc((size_t)N_NODES * D * 4);
    int*   csr    = (int*)alloc((size_t)NEDGE * 4);
    int*   offs   = (int*)alloc((size_t)(N_NODES + 1) * 4);
    int*   cursor = (int*)alloc((size_t)N_NODES * 4);
    int*   degi   = (int*)alloc((size_t)N_NODES * 4);
    float* invdeg = (float*)alloc((size_t)N_NODES * 4);
    int*   bsum   = (int*)alloc(1024);
    float* sums   = (float*)alloc(256 * 4);
    float* scale  = (float*)alloc(128 * 4);
    float* shift  = (float*)alloc(128 * 4);

    const int NB_E = (NEDGE + 255) / 256;       // 3125
    const int NB_N = (N_NODES + 255) / 256;     // 196
    const int NB_A = (N_NODES + 7) / 8;         // 6250
    const int NB_G = (N_NODES + 63) / 64;       // 782

    // ---- CSR build (once, reused by all 3 layers) ----
    hipMemsetAsync(degi, 0, (size_t)N_NODES * 4, stream);
    k_deg<<<NB_E, 256, 0, stream>>>(dst, degi);
    k_scan1<<<NB_N, 256, 0, stream>>>(degi, offs, bsum);
    k_scan2<<<1, 256, 0, stream>>>(bsum, NB_N);
    k_scan3<<<NB_N, 256, 0, stream>>>(degi, bsum, offs, cursor, invdeg);
    k_fill<<<NB_E, 256, 0, stream>>>(src, dst, cursor, csr);

    // ---- Layer 1 ----
    k_agg<<<NB_A, 256, 0, stream>>>(x, offs, csr, invdeg, scale, shift, 0, hn);
    hipMemsetAsync(sums, 0, 256 * 4, stream);
    k_gemm<<<NB_G, 256, 0, stream>>>(x, hn, Ws1, Wn1, b1, scale, shift, 0, h1, 1, sums);
    k_bnfin<<<1, 128, 0, stream>>>(sums, g1, be1, scale, shift);

    // ---- Layer 2 (BN1+ReLU applied on read) ----
    k_agg<<<NB_A, 256, 0, stream>>>(h1, offs, csr, invdeg, scale, shift, 1, hn);
    hipMemsetAsync(sums, 0, 256 * 4, stream);
    k_gemm<<<NB_G, 256, 0, stream>>>(h1, hn, Ws2, Wn2, b2, scale, shift, 1, h2, 1, sums);
    k_bnfin<<<1, 128, 0, stream>>>(sums, g2, be2, scale, shift);

    // ---- Layer 3 (BN2+ReLU applied on read, no stats) ----
    k_agg<<<NB_A, 256, 0, stream>>>(h2, offs, csr, invdeg, scale, shift, 1, hn);
    k_gemm<<<NB_G, 256, 0, stream>>>(h2, hn, Ws3, Wn3, b3, scale, shift, 1, out, 0, sums);
}

// Round 2
// 547.064 us; speedup vs baseline: 1.5172x; 1.5172x over previous
//
#include <hip/hip_runtime.h>

#define N_NODES 50000
#define NEDGE   800000
#define D       128
#define EPS     1e-5f

typedef __attribute__((ext_vector_type(8))) short bf16x8;
typedef __attribute__((ext_vector_type(4))) float f32x4;

// fp32 -> bf16 (RNE) as ushort bits
__device__ inline uint32_t bfhi(float f) {
    uint32_t u = __float_as_uint(f);
    u += 0x7fffu + ((u >> 16) & 1u);
    return u >> 16;
}
__device__ inline float bff(uint32_t h) { return __uint_as_float(h << 16); }

// ---------------- degree count ----------------
__global__ __launch_bounds__(256) void k_deg(const int* __restrict__ dst,
                                             int* __restrict__ degi) {
    int e = blockIdx.x * 256 + threadIdx.x;
    if (e < NEDGE) atomicAdd(&degi[dst[e]], 1);
}

// ---------------- exclusive scan (3 kernels) ----------------
__global__ __launch_bounds__(256) void k_scan1(const int* __restrict__ degi,
                                               int* __restrict__ offs,
                                               int* __restrict__ bsum) {
    __shared__ int s[256];
    int tid = threadIdx.x;
    int i = blockIdx.x * 256 + tid;
    int v = (i < N_NODES) ? degi[i] : 0;
    s[tid] = v;
    __syncthreads();
    for (int d = 1; d < 256; d <<= 1) {
        int t = (tid >= d) ? s[tid - d] : 0;
        __syncthreads();
        s[tid] += t;
        __syncthreads();
    }
    if (i < N_NODES) offs[i] = s[tid] - v;   // exclusive
    if (tid == 255) bsum[blockIdx.x] = s[255];
}

__global__ __launch_bounds__(256) void k_scan2(int* __restrict__ bsum, int nb) {
    __shared__ int s[256];
    int tid = threadIdx.x;
    int v = (tid < nb) ? bsum[tid] : 0;
    s[tid] = v;
    __syncthreads();
    for (int d = 1; d < 256; d <<= 1) {
        int t = (tid >= d) ? s[tid - d] : 0;
        __syncthreads();
        s[tid] += t;
        __syncthreads();
    }
    if (tid < nb) bsum[tid] = s[tid] - v;    // exclusive block offsets
}

__global__ __launch_bounds__(256) void k_scan3(const int* __restrict__ degi,
                                               const int* __restrict__ bsum,
                                               int* __restrict__ offs,
                                               int* __restrict__ cursor,
                                               float* __restrict__ invdeg) {
    int i = blockIdx.x * 256 + threadIdx.x;
    if (i < N_NODES) {
        int o = offs[i] + bsum[blockIdx.x];
        offs[i] = o;
        cursor[i] = o;
        int dg = degi[i];
        invdeg[i] = 1.0f / (float)(dg > 0 ? dg : 1);
    }
    if (i == 0 && blockIdx.x == 0) offs[N_NODES] = NEDGE;
}

// ---------------- CSR bucket fill ----------------
__global__ __launch_bounds__(256) void k_fill(const int* __restrict__ src,
                                              const int* __restrict__ dst,
                                              int* __restrict__ cursor,
                                              int* __restrict__ csr) {
    int e = blockIdx.x * 256 + threadIdx.x;
    if (e < NEDGE) {
        int p = atomicAdd(&cursor[dst[e]], 1);
        csr[p] = src[e];
    }
}

// ---------------- mean aggregation (gather over CSR) ----------------
__global__ __launch_bounds__(256) void k_agg(const float* __restrict__ X,
                                             const int* __restrict__ offs,
                                             const int* __restrict__ csr,
                                             const float* __restrict__ invdeg,
                                             const float* __restrict__ bnscale,
                                             const float* __restrict__ bnshift,
                                             int useBn,
                                             float* __restrict__ HN) {
    int n = blockIdx.x * 8 + (threadIdx.x >> 5);
    if (n >= N_NODES) return;
    int c = (threadIdx.x & 31) * 4;

    float4 sc = {1.f, 1.f, 1.f, 1.f}, sh = {0.f, 0.f, 0.f, 0.f};
    if (useBn) {
        sc = *reinterpret_cast<const float4*>(bnscale + c);
        sh = *reinterpret_cast<const float4*>(bnshift + c);
    }
    int e0 = offs[n], e1 = offs[n + 1];
    float ax = 0.f, ay = 0.f, az = 0.f, aw = 0.f;
    for (int e = e0; e < e1; ++e) {
        int s = csr[e];
        float4 v = *reinterpret_cast<const float4*>(X + (size_t)s * D + c);
        if (useBn) {
            v.x = fmaxf(v.x * sc.x + sh.x, 0.f);
            v.y = fmaxf(v.y * sc.y + sh.y, 0.f);
            v.z = fmaxf(v.z * sc.z + sh.z, 0.f);
            v.w = fmaxf(v.w * sc.w + sh.w, 0.f);
        }
        ax += v.x; ay += v.y; az += v.z; aw += v.w;
    }
    float id = invdeg[n];
    float4 o = {ax * id, ay * id, az * id, aw * id};
    *reinterpret_cast<float4*>(HN + (size_t)n * D + c) = o;
}

// ---------------- weight prep: transpose + split fp32 -> bf16 hi/lo ----------------
// wt layout per matrix (32768 ushorts): [hiT 128x128][loT 128x128], n-major: [n][k]
__global__ __launch_bounds__(256) void k_wprep(const float* __restrict__ W0,
                                               const float* __restrict__ W1,
                                               const float* __restrict__ W2,
                                               const float* __restrict__ W3,
                                               const float* __restrict__ W4,
                                               const float* __restrict__ W5,
                                               unsigned short* __restrict__ wt) {
    int mat = blockIdx.x >> 6;            // 64 blocks per matrix
    const float* srcs[6] = {W0, W1, W2, W3, W4, W5};
    const float* W = srcs[mat];
    int t = (blockIdx.x & 63) * 256 + threadIdx.x;  // 0..16383
    int k = t >> 7;
    int n = t & 127;
    float w = W[k * 128 + n];
    uint32_t h = bfhi(w);
    uint32_t l = bfhi(w - bff(h));
    unsigned short* base = wt + (size_t)mat * 32768;
    base[n * 128 + k] = (unsigned short)h;
    base[16384 + n * 128 + k] = (unsigned short)l;
}

// ---------------- MFMA GEMM: OUT = bnrelu?(X)@Ws + HN@Wn + b (split-bf16) ----------
// 512 threads (8 waves), M-tile = 32. Wave w owns output cols [16w, 16w+16).
// LDS: 4 halves (Xhi,Xlo,Ahi,Alo), each [16 kslots][32 rows] of 16B, XOR-swizzled.
__global__ __launch_bounds__(512) void k_mm(const float* __restrict__ X,
                                            const float* __restrict__ HN,
                                            const unsigned short* __restrict__ WsT,
                                            const unsigned short* __restrict__ WnT,
                                            const float* __restrict__ bias,
                                            const float* __restrict__ bnscale,
                                            const float* __restrict__ bnshift,
                                            int useBn,
                                            float* __restrict__ OUT,
                                            int doStats,
                                            float* __restrict__ sums) {
    __shared__ __align__(16) unsigned char smem[4 * 8192];

    const int tid = threadIdx.x;
    const int lane = tid & 63;
    const int wave = tid >> 6;
    const int row0 = blockIdx.x * 32;

    // ---- B fragments: 4 k-chunks x {Ws_hi, Ws_lo, Wn_hi, Wn_lo} in registers ----
    const int col = (wave << 4) + (lane & 15);
    const int kb = (lane >> 4) * 8;
    bf16x8 wsh[4], wsl[4], wnh[4], wnl[4];
#pragma unroll
    for (int kc = 0; kc < 4; ++kc) {
        int ko = kc * 32 + kb;
        wsh[kc] = *reinterpret_cast<const bf16x8*>(WsT + (size_t)col * 128 + ko);
        wsl[kc] = *reinterpret_cast<const bf16x8*>(WsT + 16384 + (size_t)col * 128 + ko);
        wnh[kc] = *reinterpret_cast<const bf16x8*>(WnT + (size_t)col * 128 + ko);
        wnl[kc] = *reinterpret_cast<const bf16x8*>(WnT + 16384 + (size_t)col * 128 + ko);
    }

    // ---- stage X, HN -> LDS as bf16 hi/lo, fragment-ordered ----
    {
        int r = tid >> 4;          // 0..31 row in tile
        int ks = tid & 15;         // 0..15 k-slot (8 elems)
        int grow = row0 + r;
        float f[8], a[8];
        if (grow < N_NODES) {
            const float* xp = X + (size_t)grow * D + ks * 8;
            float4 x0 = *reinterpret_cast<const float4*>(xp);
            float4 x1 = *reinterpret_cast<const float4*>(xp + 4);
            if (useBn) {
                float4 s0 = *reinterpret_cast<const float4*>(bnscale + ks * 8);
                float4 s1 = *reinterpret_cast<const float4*>(bnscale + ks * 8 + 4);
                float4 h0 = *reinterpret_cast<const float4*>(bnshift + ks * 8);
                float4 h1 = *reinterpret_cast<const float4*>(bnshift + ks * 8 + 4);
                x0.x = fmaxf(x0.x * s0.x + h0.x, 0.f);
                x0.y = fmaxf(x0.y * s0.y + h0.y, 0.f);
                x0.z = fmaxf(x0.z * s0.z + h0.z, 0.f);
                x0.w = fmaxf(x0.w * s0.w + h0.w, 0.f);
                x1.x = fmaxf(x1.x * s1.x + h1.x, 0.f);
                x1.y = fmaxf(x1.y * s1.y + h1.y, 0.f);
                x1.z = fmaxf(x1.z * s1.z + h1.z, 0.f);
                x1.w = fmaxf(x1.w * s1.w + h1.w, 0.f);
            }
            const float* ap = HN + (size_t)grow * D + ks * 8;
            float4 a0 = *reinterpret_cast<const float4*>(ap);
            float4 a1 = *reinterpret_cast<const float4*>(ap + 4);
            f[0] = x0.x; f[1] = x0.y; f[2] = x0.z; f[3] = x0.w;
            f[4] = x1.x; f[5] = x1.y; f[6] = x1.z; f[7] = x1.w;
            a[0] = a0.x; a[1] = a0.y; a[2] = a0.z; a[3] = a0.w;
            a[4] = a1.x; a[5] = a1.y; a[6] = a1.z; a[7] = a1.w;
        } else {
#pragma unroll
            for (int i = 0; i < 8; ++i) { f[i] = 0.f; a[i] = 0.f; }
        }
        uint32_t hx[8], hA[8];
        int4 vhi, vlo;
        int base = ks * 512 + ((r * 16) ^ ((ks & 7) << 4));
#pragma unroll
        for (int i = 0; i < 8; ++i) hx[i] = bfhi(f[i]);
        vhi.x = hx[0] | (hx[1] << 16); vhi.y = hx[2] | (hx[3] << 16);
        vhi.z = hx[4] | (hx[5] << 16); vhi.w = hx[6] | (hx[7] << 16);
        {
            uint32_t l0 = bfhi(f[0] - bff(hx[0])), l1 = bfhi(f[1] - bff(hx[1]));
            uint32_t l2 = bfhi(f[2] - bff(hx[2])), l3 = bfhi(f[3] - bff(hx[3]));
            uint32_t l4 = bfhi(f[4] - bff(hx[4])), l5 = bfhi(f[5] - bff(hx[5]));
            uint32_t l6 = bfhi(f[6] - bff(hx[6])), l7 = bfhi(f[7] - bff(hx[7]));
            vlo.x = l0 | (l1 << 16); vlo.y = l2 | (l3 << 16);
            vlo.z = l4 | (l5 << 16); vlo.w = l6 | (l7 << 16);
        }
        *reinterpret_cast<int4*>(smem + 0 * 8192 + base) = vhi;
        *reinterpret_cast<int4*>(smem + 1 * 8192 + base) = vlo;
#pragma unroll
        for (int i = 0; i < 8; ++i) hA[i] = bfhi(a[i]);
        vhi.x = hA[0] | (hA[1] << 16); vhi.y = hA[2] | (hA[3] << 16);
        vhi.z = hA[4] | (hA[5] << 16); vhi.w = hA[6] | (hA[7] << 16);
        {
            uint32_t l0 = bfhi(a[0] - bff(hA[0])), l1 = bfhi(a[1] - bff(hA[1]));
            uint32_t l2 = bfhi(a[2] - bff(hA[2])), l3 = bfhi(a[3] - bff(hA[3]));
            uint32_t l4 = bfhi(a[4] - bff(hA[4])), l5 = bfhi(a[5] - bff(hA[5]));
            uint32_t l6 = bfhi(a[6] - bff(hA[6])), l7 = bfhi(a[7] - bff(hA[7]));
            vlo.x = l0 | (l1 << 16); vlo.y = l2 | (l3 << 16);
            vlo.z = l4 | (l5 << 16); vlo.w = l6 | (l7 << 16);
        }
        *reinterpret_cast<int4*>(smem + 2 * 8192 + base) = vhi;
        *reinterpret_cast<int4*>(smem + 3 * 8192 + base) = vlo;
    }
    __syncthreads();

    // ---- MFMA main: 2 m-subtiles x 4 k-chunks x 6 products ----
    f32x4 acc0 = {0.f, 0.f, 0.f, 0.f};
    f32x4 acc1 = {0.f, 0.f, 0.f, 0.f};
    const int mlo = lane & 15;
#pragma unroll
    for (int kc = 0; kc < 4; ++kc) {
        int ksr = kc * 4 + (lane >> 4);
        int swz = (ksr & 7) << 4;
        int o0 = ksr * 512 + ((mlo * 16) ^ swz);
        int o1 = ksr * 512 + (((16 + mlo) * 16) ^ swz);
        bf16x8 xh0 = *reinterpret_cast<const bf16x8*>(smem + 0 * 8192 + o0);
        bf16x8 xl0 = *reinterpret_cast<const bf16x8*>(smem + 1 * 8192 + o0);
        bf16x8 ah0 = *reinterpret_cast<const bf16x8*>(smem + 2 * 8192 + o0);
        bf16x8 al0 = *reinterpret_cast<const bf16x8*>(smem + 3 * 8192 + o0);
        bf16x8 xh1 = *reinterpret_cast<const bf16x8*>(smem + 0 * 8192 + o1);
        bf16x8 xl1 = *reinterpret_cast<const bf16x8*>(smem + 1 * 8192 + o1);
        bf16x8 ah1 = *reinterpret_cast<const bf16x8*>(smem + 2 * 8192 + o1);
        bf16x8 al1 = *reinterpret_cast<const bf16x8*>(smem + 3 * 8192 + o1);

        acc0 = __builtin_amdgcn_mfma_f32_16x16x32_bf16(xh0, wsh[kc], acc0, 0, 0, 0);
        acc1 = __builtin_amdgcn_mfma_f32_16x16x32_bf16(xh1, wsh[kc], acc1, 0, 0, 0);
        acc0 = __builtin_amdgcn_mfma_f32_16x16x32_bf16(xh0, wsl[kc], acc0, 0, 0, 0);
        acc1 = __builtin_amdgcn_mfma_f32_16x16x32_bf16(xh1, wsl[kc], acc1, 0, 0, 0);
        acc0 = __builtin_amdgcn_mfma_f32_16x16x32_bf16(xl0, wsh[kc], acc0, 0, 0, 0);
        acc1 = __builtin_amdgcn_mfma_f32_16x16x32_bf16(xl1, wsh[kc], acc1, 0, 0, 0);
        acc0 = __builtin_amdgcn_mfma_f32_16x16x32_bf16(ah0, wnh[kc], acc0, 0, 0, 0);
        acc1 = __builtin_amdgcn_mfma_f32_16x16x32_bf16(ah1, wnh[kc], acc1, 0, 0, 0);
        acc0 = __builtin_amdgcn_mfma_f32_16x16x32_bf16(ah0, wnl[kc], acc0, 0, 0, 0);
        acc1 = __builtin_amdgcn_mfma_f32_16x16x32_bf16(ah1, wnl[kc], acc1, 0, 0, 0);
        acc0 = __builtin_amdgcn_mfma_f32_16x16x32_bf16(al0, wnh[kc], acc0, 0, 0, 0);
        acc1 = __builtin_amdgcn_mfma_f32_16x16x32_bf16(al1, wnh[kc], acc1, 0, 0, 0);
    }

    // ---- epilogue: bias, store, fused BN stats ----
    float bcol = bias[col];
    float cs = 0.f, cq = 0.f;
#pragma unroll
    for (int r = 0; r < 4; ++r) {
        int grow = row0 + (lane >> 4) * 4 + r;
        if (grow < N_NODES) {
            float v = acc0[r] + bcol;
            OUT[(size_t)grow * D + col] = v;
            cs += v; cq += v * v;
        }
    }
#pragma unroll
    for (int r = 0; r < 4; ++r) {
        int grow = row0 + 16 + (lane >> 4) * 4 + r;
        if (grow < N_NODES) {
            float v = acc1[r] + bcol;
            OUT[(size_t)grow * D + col] = v;
            cs += v; cq += v * v;
        }
    }
    if (doStats) {
        cs += __shfl_xor(cs, 16); cs += __shfl_xor(cs, 32);
        cq += __shfl_xor(cq, 16); cq += __shfl_xor(cq, 32);
        if (lane < 16) {
            atomicAdd(&sums[col], cs);
            atomicAdd(&sums[128 + col], cq);
        }
    }
}

// ---------------- BN finalize: per-column scale/shift ----------------
__global__ void k_bnfin(const float* __restrict__ sums,
                        const float* __restrict__ gamma,
                        const float* __restrict__ beta,
                        float* __restrict__ scale,
                        float* __restrict__ shift) {
    int c = threadIdx.x;  // 128 threads
    const float invN = 1.0f / (float)N_NODES;
    float mu = sums[c] * invN;
    float var = sums[128 + c] * invN - mu * mu;
    float s = gamma[c] * rsqrtf(var + EPS);
    scale[c] = s;
    shift[c] = beta[c] - mu * s;
}

// ---------------- launch ----------------
extern "C" void kernel_launch(void* const* d_in, const int* in_sizes, int n_in,
                              void* d_out, int out_size, void* d_ws, size_t ws_size,
                              hipStream_t stream) {
    const float* x   = (const float*)d_in[0];
    const int*   src = (const int*)d_in[1];
    const int*   dst = (const int*)d_in[2];
    const float* Ws1 = (const float*)d_in[3];
    const float* Wn1 = (const float*)d_in[4];
    const float* b1  = (const float*)d_in[5];
    const float* g1  = (const float*)d_in[6];
    const float* be1 = (const float*)d_in[7];
    const float* Ws2 = (const float*)d_in[8];
    const float* Wn2 = (const float*)d_in[9];
    const float* b2  = (const float*)d_in[10];
    const float* g2  = (const float*)d_in[11];
    const float* be2 = (const float*)d_in[12];
    const float* Ws3 = (const float*)d_in[13];
    const float* Wn3 = (const float*)d_in[14];
    const float* b3  = (const float*)d_in[15];
    float* out = (float*)d_out;

    char* p = (char*)d_ws;
    auto alloc = [&](size_t bytes) -> char* {
        char* r = p;
        p += (bytes + 255) & ~(size_t)255;
        return r;
    };
    float* hn     = (float*)alloc((size_t)N_NODES * D * 4);
    float* h1     = (float*)alloc((size_t)N_NODES * D * 4);
    float* h2     = (float*)alloc((size_t)N_NODES * D * 4);
    int*   csr    = (int*)alloc((size_t)NEDGE * 4);
    int*   offs   = (int*)alloc((size_t)(N_NODES + 1) * 4);
    int*   cursor = (int*)alloc((size_t)N_NODES * 4);
    int*   degi   = (int*)alloc((size_t)N_NODES * 4);
    float* invdeg = (float*)alloc((size_t)N_NODES * 4);
    int*   bsum   = (int*)alloc(1024);
    float* sums   = (float*)alloc(256 * 4);
    float* scale  = (float*)alloc(128 * 4);
    float* shift  = (float*)alloc(128 * 4);
    unsigned short* wt = (unsigned short*)alloc((size_t)6 * 32768 * 2);

    const int NB_E = (NEDGE + 255) / 256;       // 3125
    const int NB_N = (N_NODES + 255) / 256;     // 196
    const int NB_A = (N_NODES + 7) / 8;         // 6250
    const int NB_M = (N_NODES + 31) / 32;       // 1563

    const unsigned short* WsT1 = wt + 0 * 32768;
    const unsigned short* WnT1 = wt + 1 * 32768;
    const unsigned short* WsT2 = wt + 2 * 32768;
    const unsigned short* WnT2 = wt + 3 * 32768;
    const unsigned short* WsT3 = wt + 4 * 32768;
    const unsigned short* WnT3 = wt + 5 * 32768;

    // ---- weight prep + CSR build (once, reused by all 3 layers) ----
    k_wprep<<<384, 256, 0, stream>>>(Ws1, Wn1, Ws2, Wn2, Ws3, Wn3, wt);
    hipMemsetAsync(degi, 0, (size_t)N_NODES * 4, stream);
    k_deg<<<NB_E, 256, 0, stream>>>(dst, degi);
    k_scan1<<<NB_N, 256, 0, stream>>>(degi, offs, bsum);
    k_scan2<<<1, 256, 0, stream>>>(bsum, NB_N);
    k_scan3<<<NB_N, 256, 0, stream>>>(degi, bsum, offs, cursor, invdeg);
    k_fill<<<NB_E, 256, 0, stream>>>(src, dst, cursor, csr);

    // ---- Layer 1 ----
    k_agg<<<NB_A, 256, 0, stream>>>(x, offs, csr, invdeg, scale, shift, 0, hn);
    hipMemsetAsync(sums, 0, 256 * 4, stream);
    k_mm<<<NB_M, 512, 0, stream>>>(x, hn, WsT1, WnT1, b1, scale, shift, 0, h1, 1, sums);
    k_bnfin<<<1, 128, 0, stream>>>(sums, g1, be1, scale, shift);

    // ---- Layer 2 (BN1+ReLU applied on read) ----
    k_agg<<<NB_A, 256, 0, stream>>>(h1, offs, csr, invdeg, scale, shift, 1, hn);
    hipMemsetAsync(sums, 0, 256 * 4, stream);
    k_mm<<<NB_M, 512, 0, stream>>>(h1, hn, WsT2, WnT2, b2, scale, shift, 1, h2, 1, sums);
    k_bnfin<<<1, 128, 0, stream>>>(sums, g2, be2, scale, shift);

    // ---- Layer 3 (BN2+ReLU applied on read, no stats) ----
    k_agg<<<NB_A, 256, 0, stream>>>(h2, offs, csr, invdeg, scale, shift, 1, hn);
    k_mm<<<NB_M, 512, 0, stream>>>(h2, hn, WsT3, WnT3, b3, scale, shift, 1, out, 0, sums);
}

// Round 3
// 440.997 us; speedup vs baseline: 1.8821x; 1.2405x over previous
//
#include <hip/hip_runtime.h>

#define N_NODES 50000
#define NEDGE   800000
#define D       128
#define EPS     1e-5f

typedef __attribute__((ext_vector_type(8))) short bf16x8;
typedef __attribute__((ext_vector_type(4))) float f32x4;
typedef __attribute__((ext_vector_type(8))) unsigned short u16x8;

// fp32 -> bf16 (RNE) as ushort bits
__device__ inline uint32_t bfhi(float f) {
    uint32_t u = __float_as_uint(f);
    u += 0x7fffu + ((u >> 16) & 1u);
    return u >> 16;
}
__device__ inline float bff(uint32_t h) { return __uint_as_float(h << 16); }

// ---------------- degree count ----------------
__global__ __launch_bounds__(256) void k_deg(const int* __restrict__ dst,
                                             int* __restrict__ degi) {
    int e = blockIdx.x * 256 + threadIdx.x;
    if (e < NEDGE) atomicAdd(&degi[dst[e]], 1);
}

// ---------------- exclusive scan (3 kernels) ----------------
__global__ __launch_bounds__(256) void k_scan1(const int* __restrict__ degi,
                                               int* __restrict__ offs,
                                               int* __restrict__ bsum) {
    __shared__ int s[256];
    int tid = threadIdx.x;
    int i = blockIdx.x * 256 + tid;
    int v = (i < N_NODES) ? degi[i] : 0;
    s[tid] = v;
    __syncthreads();
    for (int d = 1; d < 256; d <<= 1) {
        int t = (tid >= d) ? s[tid - d] : 0;
        __syncthreads();
        s[tid] += t;
        __syncthreads();
    }
    if (i < N_NODES) offs[i] = s[tid] - v;   // exclusive
    if (tid == 255) bsum[blockIdx.x] = s[255];
}

__global__ __launch_bounds__(256) void k_scan2(int* __restrict__ bsum, int nb) {
    __shared__ int s[256];
    int tid = threadIdx.x;
    int v = (tid < nb) ? bsum[tid] : 0;
    s[tid] = v;
    __syncthreads();
    for (int d = 1; d < 256; d <<= 1) {
        int t = (tid >= d) ? s[tid - d] : 0;
        __syncthreads();
        s[tid] += t;
        __syncthreads();
    }
    if (tid < nb) bsum[tid] = s[tid] - v;    // exclusive block offsets
}

__global__ __launch_bounds__(256) void k_scan3(const int* __restrict__ degi,
                                               const int* __restrict__ bsum,
                                               int* __restrict__ offs,
                                               int* __restrict__ cursor,
                                               float* __restrict__ invdeg) {
    int i = blockIdx.x * 256 + threadIdx.x;
    if (i < N_NODES) {
        int o = offs[i] + bsum[blockIdx.x];
        offs[i] = o;
        cursor[i] = o;
        int dg = degi[i];
        invdeg[i] = 1.0f / (float)(dg > 0 ? dg : 1);
    }
    if (i == 0 && blockIdx.x == 0) offs[N_NODES] = NEDGE;
}

// ---------------- CSR bucket fill ----------------
__global__ __launch_bounds__(256) void k_fill(const int* __restrict__ src,
                                              const int* __restrict__ dst,
                                              int* __restrict__ cursor,
                                              int* __restrict__ csr) {
    int e = blockIdx.x * 256 + threadIdx.x;
    if (e < NEDGE) {
        int p = atomicAdd(&cursor[dst[e]], 1);
        csr[p] = src[e];
    }
}

// ---------------- fp32 -> bf16(hi) plane (for layer-1 gather) ----------------
__global__ __launch_bounds__(256) void k_tobf16(const float* __restrict__ X,
                                                unsigned short* __restrict__ XB) {
    int t = blockIdx.x * 256 + threadIdx.x;   // 800000 units of 8 elems
    if (t >= (N_NODES * D) / 8) return;
    const float* p = X + (size_t)t * 8;
    float4 a = *reinterpret_cast<const float4*>(p);
    float4 b = *reinterpret_cast<const float4*>(p + 4);
    u16x8 o;
    o[0] = (unsigned short)bfhi(a.x); o[1] = (unsigned short)bfhi(a.y);
    o[2] = (unsigned short)bfhi(a.z); o[3] = (unsigned short)bfhi(a.w);
    o[4] = (unsigned short)bfhi(b.x); o[5] = (unsigned short)bfhi(b.y);
    o[6] = (unsigned short)bfhi(b.z); o[7] = (unsigned short)bfhi(b.w);
    *reinterpret_cast<u16x8*>(XB + (size_t)t * 8) = o;
}

// ---------------- mean aggregation: gather bf16(hi) rows over CSR ----------------
// 16 nodes per 256-thread block; 16 lanes per node, u16x8 (16B) per lane.
__global__ __launch_bounds__(256) void k_agg(const unsigned short* __restrict__ XB,
                                             const int* __restrict__ offs,
                                             const int* __restrict__ csr,
                                             const float* __restrict__ invdeg,
                                             const float* __restrict__ bnscale,
                                             const float* __restrict__ bnshift,
                                             int useBn,
                                             float* __restrict__ HN) {
    int n = blockIdx.x * 16 + (threadIdx.x >> 4);
    if (n >= N_NODES) return;
    int c = (threadIdx.x & 15) * 8;

    float sc[8], sh[8];
    if (useBn) {
        float4 s0 = *reinterpret_cast<const float4*>(bnscale + c);
        float4 s1 = *reinterpret_cast<const float4*>(bnscale + c + 4);
        float4 h0 = *reinterpret_cast<const float4*>(bnshift + c);
        float4 h1 = *reinterpret_cast<const float4*>(bnshift + c + 4);
        sc[0] = s0.x; sc[1] = s0.y; sc[2] = s0.z; sc[3] = s0.w;
        sc[4] = s1.x; sc[5] = s1.y; sc[6] = s1.z; sc[7] = s1.w;
        sh[0] = h0.x; sh[1] = h0.y; sh[2] = h0.z; sh[3] = h0.w;
        sh[4] = h1.x; sh[5] = h1.y; sh[6] = h1.z; sh[7] = h1.w;
    }

    int e0 = offs[n], e1 = offs[n + 1];
    float acc[8];
#pragma unroll
    for (int i = 0; i < 8; ++i) acc[i] = 0.f;

    for (int e = e0; e < e1; ++e) {
        int s = csr[e];
        u16x8 v = *reinterpret_cast<const u16x8*>(XB + (size_t)s * D + c);
        if (useBn) {
#pragma unroll
            for (int i = 0; i < 8; ++i)
                acc[i] += fmaxf(bff((unsigned short)v[i]) * sc[i] + sh[i], 0.f);
        } else {
#pragma unroll
            for (int i = 0; i < 8; ++i)
                acc[i] += bff((unsigned short)v[i]);
        }
    }
    float id = invdeg[n];
    float4 o0 = {acc[0] * id, acc[1] * id, acc[2] * id, acc[3] * id};
    float4 o1 = {acc[4] * id, acc[5] * id, acc[6] * id, acc[7] * id};
    *reinterpret_cast<float4*>(HN + (size_t)n * D + c) = o0;
    *reinterpret_cast<float4*>(HN + (size_t)n * D + c + 4) = o1;
}

// ---------------- weight prep: transpose + split fp32 -> bf16 hi/lo ----------------
__global__ __launch_bounds__(256) void k_wprep(const float* __restrict__ W0,
                                               const float* __restrict__ W1,
                                               const float* __restrict__ W2,
                                               const float* __restrict__ W3,
                                               const float* __restrict__ W4,
                                               const float* __restrict__ W5,
                                               unsigned short* __restrict__ wt) {
    int mat = blockIdx.x >> 6;            // 64 blocks per matrix
    const float* srcs[6] = {W0, W1, W2, W3, W4, W5};
    const float* W = srcs[mat];
    int t = (blockIdx.x & 63) * 256 + threadIdx.x;  // 0..16383
    int k = t >> 7;
    int n = t & 127;
    float w = W[k * 128 + n];
    uint32_t h = bfhi(w);
    uint32_t l = bfhi(w - bff(h));
    unsigned short* base = wt + (size_t)mat * 32768;
    base[n * 128 + k] = (unsigned short)h;
    base[16384 + n * 128 + k] = (unsigned short)l;
}

// ---------------- MFMA GEMM: OUT = bnrelu?(X)@Ws + HN@Wn + b (split-bf16) ----------
// 512 threads (8 waves), M-tile = 64. Wave w owns output cols [16w, 16w+16),
// 4 m-subtiles of 16 rows. LDS: 4 planes (Xhi,Xlo,Ahi,Alo), row stride 272B (pad).
#define LDS_RS 272
#define LDS_PLANE (64 * LDS_RS)
__global__ __launch_bounds__(512) void k_mm(const float* __restrict__ Xf,
                                            const unsigned short* __restrict__ Xhi,
                                            const unsigned short* __restrict__ Xlo,
                                            const float* __restrict__ HN,
                                            const unsigned short* __restrict__ WsT,
                                            const unsigned short* __restrict__ WnT,
                                            const float* __restrict__ bias,
                                            const float* __restrict__ bnscale,
                                            const float* __restrict__ bnshift,
                                            int mode,        // 0: Xf, no BN; 1: Xhi/Xlo + BN+ReLU
                                            float* __restrict__ OUTf,
                                            unsigned short* __restrict__ OUThi,
                                            unsigned short* __restrict__ OUTlo,
                                            int outFp32,
                                            int doStats,
                                            float* __restrict__ sums) {
    __shared__ __align__(16) unsigned char smem[4 * LDS_PLANE];

    const int tid = threadIdx.x;
    const int lane = tid & 63;
    const int wave = tid >> 6;
    const int row0 = blockIdx.x * 64;
    const int mlo = lane & 15;
    const int g = lane >> 4;
    const int col = (wave << 4) + mlo;
    const int kb = g * 8;

    // ---- B fragments: 4 k-chunks x {Ws_hi, Ws_lo, Wn_hi, Wn_lo} ----
    bf16x8 wsh[4], wsl[4], wnh[4], wnl[4];
#pragma unroll
    for (int kc = 0; kc < 4; ++kc) {
        int ko = kc * 32 + kb;
        wsh[kc] = *reinterpret_cast<const bf16x8*>(WsT + (size_t)col * 128 + ko);
        wsl[kc] = *reinterpret_cast<const bf16x8*>(WsT + 16384 + (size_t)col * 128 + ko);
        wnh[kc] = *reinterpret_cast<const bf16x8*>(WnT + (size_t)col * 128 + ko);
        wnl[kc] = *reinterpret_cast<const bf16x8*>(WnT + 16384 + (size_t)col * 128 + ko);
    }

    // ---- stage 64 rows of X (+BN) and HN into LDS as bf16 hi/lo ----
#pragma unroll
    for (int uu = 0; uu < 2; ++uu) {
        int u = tid + uu * 512;
        int r = u >> 4;
        int ks = u & 15;
        int grow = row0 + r;
        float f[8], a[8];
        if (grow < N_NODES) {
            if (mode == 0) {
                const float* xp = Xf + (size_t)grow * D + ks * 8;
                float4 x0 = *reinterpret_cast<const float4*>(xp);
                float4 x1 = *reinterpret_cast<const float4*>(xp + 4);
                f[0] = x0.x; f[1] = x0.y; f[2] = x0.z; f[3] = x0.w;
                f[4] = x1.x; f[5] = x1.y; f[6] = x1.z; f[7] = x1.w;
            } else {
                u16x8 hi = *reinterpret_cast<const u16x8*>(Xhi + (size_t)grow * D + ks * 8);
                u16x8 lo = *reinterpret_cast<const u16x8*>(Xlo + (size_t)grow * D + ks * 8);
                float4 s0 = *reinterpret_cast<const float4*>(bnscale + ks * 8);
                float4 s1 = *reinterpret_cast<const float4*>(bnscale + ks * 8 + 4);
                float4 h0 = *reinterpret_cast<const float4*>(bnshift + ks * 8);
                float4 h1 = *reinterpret_cast<const float4*>(bnshift + ks * 8 + 4);
                float scv[8] = {s0.x, s0.y, s0.z, s0.w, s1.x, s1.y, s1.z, s1.w};
                float shv[8] = {h0.x, h0.y, h0.z, h0.w, h1.x, h1.y, h1.z, h1.w};
#pragma unroll
                for (int i = 0; i < 8; ++i) {
                    float v = bff((unsigned short)hi[i]) + bff((unsigned short)lo[i]);
                    f[i] = fmaxf(v * scv[i] + shv[i], 0.f);
                }
            }
            const float* ap = HN + (size_t)grow * D + ks * 8;
            float4 a0 = *reinterpret_cast<const float4*>(ap);
            float4 a1 = *reinterpret_cast<const float4*>(ap + 4);
            a[0] = a0.x; a[1] = a0.y; a[2] = a0.z; a[3] = a0.w;
            a[4] = a1.x; a[5] = a1.y; a[6] = a1.z; a[7] = a1.w;
        } else {
#pragma unroll
            for (int i = 0; i < 8; ++i) { f[i] = 0.f; a[i] = 0.f; }
        }
        int base = r * LDS_RS + ks * 16;
        uint32_t h8[8];
        int4 vhi, vlo;
#pragma unroll
        for (int i = 0; i < 8; ++i) h8[i] = bfhi(f[i]);
        vhi.x = h8[0] | (h8[1] << 16); vhi.y = h8[2] | (h8[3] << 16);
        vhi.z = h8[4] | (h8[5] << 16); vhi.w = h8[6] | (h8[7] << 16);
        {
            uint32_t l0 = bfhi(f[0] - bff(h8[0])), l1 = bfhi(f[1] - bff(h8[1]));
            uint32_t l2 = bfhi(f[2] - bff(h8[2])), l3 = bfhi(f[3] - bff(h8[3]));
            uint32_t l4 = bfhi(f[4] - bff(h8[4])), l5 = bfhi(f[5] - bff(h8[5]));
            uint32_t l6 = bfhi(f[6] - bff(h8[6])), l7 = bfhi(f[7] - bff(h8[7]));
            vlo.x = l0 | (l1 << 16); vlo.y = l2 | (l3 << 16);
            vlo.z = l4 | (l5 << 16); vlo.w = l6 | (l7 << 16);
        }
        *reinterpret_cast<int4*>(smem + 0 * LDS_PLANE + base) = vhi;
        *reinterpret_cast<int4*>(smem + 1 * LDS_PLANE + base) = vlo;
#pragma unroll
        for (int i = 0; i < 8; ++i) h8[i] = bfhi(a[i]);
        vhi.x = h8[0] | (h8[1] << 16); vhi.y = h8[2] | (h8[3] << 16);
        vhi.z = h8[4] | (h8[5] << 16); vhi.w = h8[6] | (h8[7] << 16);
        {
            uint32_t l0 = bfhi(a[0] - bff(h8[0])), l1 = bfhi(a[1] - bff(h8[1]));
            uint32_t l2 = bfhi(a[2] - bff(h8[2])), l3 = bfhi(a[3] - bff(h8[3]));
            uint32_t l4 = bfhi(a[4] - bff(h8[4])), l5 = bfhi(a[5] - bff(h8[5]));
            uint32_t l6 = bfhi(a[6] - bff(h8[6])), l7 = bfhi(a[7] - bff(h8[7]));
            vlo.x = l0 | (l1 << 16); vlo.y = l2 | (l3 << 16);
            vlo.z = l4 | (l5 << 16); vlo.w = l6 | (l7 << 16);
        }
        *reinterpret_cast<int4*>(smem + 2 * LDS_PLANE + base) = vhi;
        *reinterpret_cast<int4*>(smem + 3 * LDS_PLANE + base) = vlo;
    }
    __syncthreads();

    // ---- MFMA main: 4 m-subtiles x 4 k-chunks x 6 products ----
    f32x4 acc[4];
#pragma unroll
    for (int s = 0; s < 4; ++s) acc[s] = (f32x4){0.f, 0.f, 0.f, 0.f};

#pragma unroll
    for (int kc = 0; kc < 4; ++kc) {
        int ksr = kc * 4 + g;
        int ko = ksr * 16;
#pragma unroll
        for (int s = 0; s < 4; ++s) {
            int ad = (s * 16 + mlo) * LDS_RS + ko;
            bf16x8 xh = *reinterpret_cast<const bf16x8*>(smem + 0 * LDS_PLANE + ad);
            bf16x8 xl = *reinterpret_cast<const bf16x8*>(smem + 1 * LDS_PLANE + ad);
            bf16x8 ah = *reinterpret_cast<const bf16x8*>(smem + 2 * LDS_PLANE + ad);
            bf16x8 al = *reinterpret_cast<const bf16x8*>(smem + 3 * LDS_PLANE + ad);
            acc[s] = __builtin_amdgcn_mfma_f32_16x16x32_bf16(xh, wsh[kc], acc[s], 0, 0, 0);
            acc[s] = __builtin_amdgcn_mfma_f32_16x16x32_bf16(xh, wsl[kc], acc[s], 0, 0, 0);
            acc[s] = __builtin_amdgcn_mfma_f32_16x16x32_bf16(xl, wsh[kc], acc[s], 0, 0, 0);
            acc[s] = __builtin_amdgcn_mfma_f32_16x16x32_bf16(ah, wnh[kc], acc[s], 0, 0, 0);
            acc[s] = __builtin_amdgcn_mfma_f32_16x16x32_bf16(ah, wnl[kc], acc[s], 0, 0, 0);
            acc[s] = __builtin_amdgcn_mfma_f32_16x16x32_bf16(al, wnh[kc], acc[s], 0, 0, 0);
        }
    }

    // ---- epilogue: bias, store (fp32 or bf16 hi/lo planes), fused BN stats ----
    float bcol = bias[col];
    float cs = 0.f, cq = 0.f;
#pragma unroll
    for (int s = 0; s < 4; ++s) {
#pragma unroll
        for (int r = 0; r < 4; ++r) {
            int grow = row0 + s * 16 + g * 4 + r;
            if (grow < N_NODES) {
                float v = acc[s][r] + bcol;
                if (outFp32) {
                    OUTf[(size_t)grow * D + col] = v;
                } else {
                    uint32_t h = bfhi(v);
                    OUThi[(size_t)grow * D + col] = (unsigned short)h;
                    OUTlo[(size_t)grow * D + col] = (unsigned short)bfhi(v - bff(h));
                }
                cs += v; cq += v * v;
            }
        }
    }
    if (doStats) {
        cs += __shfl_xor(cs, 16); cs += __shfl_xor(cs, 32);
        cq += __shfl_xor(cq, 16); cq += __shfl_xor(cq, 32);
        if (lane < 16) {
            atomicAdd(&sums[col], cs);
            atomicAdd(&sums[128 + col], cq);
        }
    }
}

// ---------------- BN finalize: per-column scale/shift ----------------
__global__ void k_bnfin(const float* __restrict__ sums,
                        const float* __restrict__ gamma,
                        const float* __restrict__ beta,
                        float* __restrict__ scale,
                        float* __restrict__ shift) {
    int c = threadIdx.x;  // 128 threads
    const float invN = 1.0f / (float)N_NODES;
    float mu = sums[c] * invN;
    float var = sums[128 + c] * invN - mu * mu;
    float s = gamma[c] * rsqrtf(var + EPS);
    scale[c] = s;
    shift[c] = beta[c] - mu * s;
}

// ---------------- launch ----------------
extern "C" void kernel_launch(void* const* d_in, const int* in_sizes, int n_in,
                              void* d_out, int out_size, void* d_ws, size_t ws_size,
                              hipStream_t stream) {
    const float* x   = (const float*)d_in[0];
    const int*   src = (const int*)d_in[1];
    const int*   dst = (const int*)d_in[2];
    const float* Ws1 = (const float*)d_in[3];
    const float* Wn1 = (const float*)d_in[4];
    const float* b1  = (const float*)d_in[5];
    const float* g1  = (const float*)d_in[6];
    const float* be1 = (const float*)d_in[7];
    const float* Ws2 = (const float*)d_in[8];
    const float* Wn2 = (const float*)d_in[9];
    const float* b2  = (const float*)d_in[10];
    const float* g2  = (const float*)d_in[11];
    const float* be2 = (const float*)d_in[12];
    const float* Ws3 = (const float*)d_in[13];
    const float* Wn3 = (const float*)d_in[14];
    const float* b3  = (const float*)d_in[15];
    float* out = (float*)d_out;

    char* p = (char*)d_ws;
    auto alloc = [&](size_t bytes) -> char* {
        char* r = p;
        p += (bytes + 255) & ~(size_t)255;
        return r;
    };
    float* hn   = (float*)alloc((size_t)N_NODES * D * 4);
    unsigned short* xb   = (unsigned short*)alloc((size_t)N_NODES * D * 2);
    unsigned short* h1hi = (unsigned short*)alloc((size_t)N_NODES * D * 2);
    unsigned short* h1lo = (unsigned short*)alloc((size_t)N_NODES * D * 2);
    unsigned short* h2hi = (unsigned short*)alloc((size_t)N_NODES * D * 2);
    unsigned short* h2lo = (unsigned short*)alloc((size_t)N_NODES * D * 2);
    int*   csr    = (int*)alloc((size_t)NEDGE * 4);
    int*   offs   = (int*)alloc((size_t)(N_NODES + 1) * 4);
    int*   cursor = (int*)alloc((size_t)N_NODES * 4);
    int*   degi   = (int*)alloc((size_t)N_NODES * 4);
    float* invdeg = (float*)alloc((size_t)N_NODES * 4);
    int*   bsum   = (int*)alloc(1024);
    float* sums   = (float*)alloc(256 * 4);
    float* scale  = (float*)alloc(128 * 4);
    float* shift  = (float*)alloc(128 * 4);
    unsigned short* wt = (unsigned short*)alloc((size_t)6 * 32768 * 2);

    const int NB_E = (NEDGE + 255) / 256;       // 3125
    const int NB_N = (N_NODES + 255) / 256;     // 196
    const int NB_A = (N_NODES + 15) / 16;       // 3125
    const int NB_M = (N_NODES + 63) / 64;       // 782
    const int NB_T = (N_NODES * D / 8 + 255) / 256;  // 3125

    const unsigned short* WsT1 = wt + 0 * 32768;
    const unsigned short* WnT1 = wt + 1 * 32768;
    const unsigned short* WsT2 = wt + 2 * 32768;
    const unsigned short* WnT2 = wt + 3 * 32768;
    const unsigned short* WsT3 = wt + 4 * 32768;
    const unsigned short* WnT3 = wt + 5 * 32768;

    // ---- weight prep + CSR build + x->bf16 (once) ----
    k_wprep<<<384, 256, 0, stream>>>(Ws1, Wn1, Ws2, Wn2, Ws3, Wn3, wt);
    hipMemsetAsync(degi, 0, (size_t)N_NODES * 4, stream);
    k_deg<<<NB_E, 256, 0, stream>>>(dst, degi);
    k_scan1<<<NB_N, 256, 0, stream>>>(degi, offs, bsum);
    k_scan2<<<1, 256, 0, stream>>>(bsum, NB_N);
    k_scan3<<<NB_N, 256, 0, stream>>>(degi, bsum, offs, cursor, invdeg);
    k_fill<<<NB_E, 256, 0, stream>>>(src, dst, cursor, csr);
    k_tobf16<<<NB_T, 256, 0, stream>>>(x, xb);

    // ---- Layer 1 ----
    k_agg<<<NB_A, 256, 0, stream>>>(xb, offs, csr, invdeg, scale, shift, 0, hn);
    hipMemsetAsync(sums, 0, 256 * 4, stream);
    k_mm<<<NB_M, 512, 0, stream>>>(x, h1hi, h1lo, hn, WsT1, WnT1, b1, scale, shift,
                                   0, out, h1hi, h1lo, 0, 1, sums);
    k_bnfin<<<1, 128, 0, stream>>>(sums, g1, be1, scale, shift);

    // ---- Layer 2 (BN1+ReLU applied on read) ----
    k_agg<<<NB_A, 256, 0, stream>>>(h1hi, offs, csr, invdeg, scale, shift, 1, hn);
    hipMemsetAsync(sums, 0, 256 * 4, stream);
    k_mm<<<NB_M, 512, 0, stream>>>(x, h1hi, h1lo, hn, WsT2, WnT2, b2, scale, shift,
                                   1, out, h2hi, h2lo, 0, 1, sums);
    k_bnfin<<<1, 128, 0, stream>>>(sums, g2, be2, scale, shift);

    // ---- Layer 3 (BN2+ReLU applied on read, fp32 out, no stats) ----
    k_agg<<<NB_A, 256, 0, stream>>>(h2hi, offs, csr, invdeg, scale, shift, 1, hn);
    k_mm<<<NB_M, 512, 0, stream>>>(x, h2hi, h2lo, hn, WsT3, WnT3, b3, scale, shift,
                                   1, out, h1hi, h1lo, 1, 0, sums);
}